// Round 19
// baseline (2011.408 us; speedup 1.0000x reference)
//
#include <hip/hip_runtime.h>
#include <hip/hip_bf16.h>
#include <math.h>

#define Dm 768
#define Tt 1024
#define Bb 2
#define Hh 12
#define DFF 4096
#define Ll 12
#define Vv 50257
#define ROWS (Bb*Tt)   // 2048
#define LN_EPS 1e-5f

// per-layer weight block (elems): [qkv 1769472 | proj 589824 | ff1 3145728 | ff2 3145728]
#define LWE 8650752
#define oPROJL 1769472
#define oFF1L 2359296
#define oFF2L 5505024
// float4 cumulative within a layer block
#define L4_Q 442368
#define L4_P 589824
#define L4_F1 1376256
#define L4_ALL 2162688
#define HEAD4 9649344          // head float4 count
#define HEADD4 25952256        // head dst offset in wb (float4 units)

typedef unsigned int uint;
typedef unsigned short ushort;
typedef float f32x4 __attribute__((ext_vector_type(4)));
typedef short bf16x8 __attribute__((ext_vector_type(8)));
typedef ushort us8 __attribute__((ext_vector_type(8)));

__device__ __forceinline__ ushort f2bf(float f) {
  uint u = __builtin_bit_cast(uint, f);
  u += 0x7FFFu + ((u >> 16) & 1u);   // RNE
  return (ushort)(u >> 16);
}

__device__ __forceinline__ ushort4 cvt4(float4 v) {
  ushort4 o;
  o.x = f2bf(v.x); o.y = f2bf(v.y); o.z = f2bf(v.z); o.w = f2bf(v.w);
  return o;
}

#define GLL(gp, lp)                                                          \
  __builtin_amdgcn_global_load_lds(                                          \
      (const __attribute__((address_space(1))) uint*)(gp),                   \
      (__attribute__((address_space(3))) uint*)(lp), 16, 0, 0)

#define MF(a, b, c) __builtin_amdgcn_mfma_f32_16x16x32_bf16(a, b, c, 0, 0, 0)

// ---------------------------------------------------------------------------
// Fused embedding + LayerNorm
// ---------------------------------------------------------------------------
__global__ __launch_bounds__(256) void embed_ln(
    const int* __restrict__ idx, const float* __restrict__ tok,
    const float* __restrict__ pos, const float* __restrict__ w,
    const float* __restrict__ b, float* __restrict__ x,
    ushort* __restrict__ out) {
  const int row = blockIdx.x;
  const int t = row & (Tt - 1);
  const int tid = threadIdx.x;
  const float* tsrc = tok + (size_t)idx[row] * Dm;
  const float* psrc = pos + (size_t)t * Dm;
  float v[3];
  float sum = 0.f, sq = 0.f;
#pragma unroll
  for (int i = 0; i < 3; i++) {
    const int d = tid + i * 256;
    v[i] = tsrc[d] + psrc[d];
    x[(size_t)row * Dm + d] = v[i];
    sum += v[i]; sq += v[i] * v[i];
  }
#pragma unroll
  for (int off = 32; off > 0; off >>= 1) {
    sum += __shfl_xor(sum, off);
    sq  += __shfl_xor(sq, off);
  }
  __shared__ float red[8];
  const int wid = tid >> 6, lane = tid & 63;
  if (lane == 0) { red[wid] = sum; red[wid + 4] = sq; }
  __syncthreads();
  sum = red[0] + red[1] + red[2] + red[3];
  sq  = red[4] + red[5] + red[6] + red[7];
  const float mu = sum * (1.f / Dm);
  const float var = sq * (1.f / Dm) - mu * mu;
  const float rstd = rsqrtf(var + LN_EPS);
  ushort* dst = out + (size_t)row * Dm;
#pragma unroll
  for (int i = 0; i < 3; i++) {
    const int d = tid + i * 256;
    dst[d] = f2bf((v[i] - mu) * rstd * w[d] + b[d]);
  }
}

// ---------------------------------------------------------------------------
// Fused split-K reduce + bias + residual + LayerNorm -> bf16 h (192 thr)
// ---------------------------------------------------------------------------
__global__ __launch_bounds__(192) void red_ln(
    const float* __restrict__ part, int nsk, const float* __restrict__ bias,
    float* __restrict__ x, const float* __restrict__ w,
    const float* __restrict__ b, ushort* __restrict__ out) {
  const int row = blockIdx.x;
  const int tid = threadIdx.x;
  const size_t o4 = (size_t)row * 192 + tid;
  float4 xv = ((const float4*)x)[o4];
  const float4 b4 = ((const float4*)bias)[tid];
  xv.x += b4.x; xv.y += b4.y; xv.z += b4.z; xv.w += b4.w;
  for (int k = 0; k < nsk; k++) {
    const float4 p = ((const float4*)part)[(size_t)k * ROWS * 192 + o4];
    xv.x += p.x; xv.y += p.y; xv.z += p.z; xv.w += p.w;
  }
  ((float4*)x)[o4] = xv;
  float sum = xv.x + xv.y + xv.z + xv.w;
  float sq = xv.x * xv.x + xv.y * xv.y + xv.z * xv.z + xv.w * xv.w;
#pragma unroll
  for (int off = 32; off > 0; off >>= 1) {
    sum += __shfl_xor(sum, off);
    sq  += __shfl_xor(sq, off);
  }
  __shared__ float red[6];
  const int wid = tid >> 6, lane = tid & 63;
  if (lane == 0) { red[wid] = sum; red[wid + 3] = sq; }
  __syncthreads();
  sum = red[0] + red[1] + red[2];
  sq  = red[3] + red[4] + red[5];
  const float mu = sum * (1.f / Dm);
  const float var = sq * (1.f / Dm) - mu * mu;
  const float rstd = rsqrtf(var + LN_EPS);
  const float4 w4 = ((const float4*)w)[tid];
  const float4 bb4 = ((const float4*)b)[tid];
  ushort4 o;
  o.x = f2bf((xv.x - mu) * rstd * w4.x + bb4.x);
  o.y = f2bf((xv.y - mu) * rstd * w4.y + bb4.y);
  o.z = f2bf((xv.z - mu) * rstd * w4.z + bb4.z);
  o.w = f2bf((xv.w - mu) * rstd * w4.w + bb4.w);
  ((ushort4*)out)[o4] = o;
}

// ---------------------------------------------------------------------------
// Pre-pass converter: layer 0 block + head (R17 structure).
// ---------------------------------------------------------------------------
__global__ __launch_bounds__(256) void convert_pre(
    const float* __restrict__ q, const float* __restrict__ p,
    const float* __restrict__ f1, const float* __restrict__ f2,
    const float* __restrict__ hd, ushort* __restrict__ wb) {
  const int total = L4_ALL + HEAD4;
  const int stride = gridDim.x * 256;
  for (int i = blockIdx.x * 256 + threadIdx.x; i < total; i += stride) {
    const float* s; int j; size_t d;
    if (i < L4_Q) { s = q; j = i; d = i; }
    else if (i < L4_P) { s = p; j = i - L4_Q; d = i; }
    else if (i < L4_F1) { s = f1; j = i - L4_P; d = i; }
    else if (i < L4_ALL) { s = f2; j = i - L4_F1; d = i; }
    else { s = hd; j = i - L4_ALL; d = (size_t)HEADD4 + j; }
    ((ushort4*)wb)[d] = cvt4(((const float4*)s)[j]);
  }
}

// ---------------------------------------------------------------------------
// bf16 MFMA GEMM (loop GEMMs) — BK=64. EPI_QKV hosts 128 converter blocks
// (bx>=18): next layer's weights, 4 independent float4/iter (4-deep MLP).
// ---------------------------------------------------------------------------
#define EPI_QKV 0
#define EPI_PART 1
#define EPI_BIAS_GELU 2
#define EPI_NONE 3

template <int EPI>
__global__ __launch_bounds__(256) void gemm_mfma(
    const ushort* __restrict__ A, const ushort* __restrict__ B,
    const float* __restrict__ bias, void* __restrict__ Cv,
    void* __restrict__ Cv2, int Kloop, int Kstr, int Nloc, int ldC,
    const float* __restrict__ nq, const float* __restrict__ np,
    const float* __restrict__ nf1, const float* __restrict__ nf2,
    ushort* __restrict__ ndst) {
  __shared__ char lds[65536];           // 2 x (A 16KB + B 16KB)
  const int tid = threadIdx.x;

  if (EPI == EPI_QKV && blockIdx.x >= 18) {
    if (nq != nullptr) {
      const int wkr = (blockIdx.x - 18) * 16 + blockIdx.y;   // 0..127
      const int n4g = L4_ALL >> 2;                           // 540672
      for (int i4 = wkr * 256 + tid; i4 < n4g; i4 += 128 * 256) {
        const int i = i4 * 4;
        const float* s; int j;
        if (i < L4_Q) { s = nq; j = i; }
        else if (i < L4_P) { s = np; j = i - L4_Q; }
        else if (i < L4_F1) { s = nf1; j = i - L4_P; }
        else { s = nf2; j = i - L4_F1; }
        const float4 v0 = ((const float4*)s)[j + 0];
        const float4 v1 = ((const float4*)s)[j + 1];
        const float4 v2 = ((const float4*)s)[j + 2];
        const float4 v3 = ((const float4*)s)[j + 3];
        ((ushort4*)ndst)[i + 0] = cvt4(v0);
        ((ushort4*)ndst)[i + 1] = cvt4(v1);
        ((ushort4*)ndst)[i + 2] = cvt4(v2);
        ((ushort4*)ndst)[i + 3] = cvt4(v3);
      }
    }
    return;
  }

  const int l = tid & 63;
  const int wid = __builtin_amdgcn_readfirstlane(tid >> 6);
  const int wr = wid >> 1, wc = wid & 1;
  const int m0 = blockIdx.y * 128;
  const int n0 = blockIdx.x * 128;
  const int z = (EPI == EPI_PART) ? blockIdx.z : 0;
  if (EPI == EPI_PART) { A += (size_t)z * Kloop; B += (size_t)z * Kloop; }

  const ushort* gA[4];
  const ushort* gB[4];
#pragma unroll
  for (int j = 0; j < 4; j++) {
    const int c = tid + j * 256;
    const int r = c >> 3;
    const int q = (c & 7) ^ (r & 7);
    gA[j] = A + (size_t)(m0 + r) * Kstr + q * 8;
    const int rb = min(n0 + r, Nloc - 1);
    gB[j] = B + (size_t)rb * Kstr + q * 8;
  }

#define LSTG(t, base)                                                        \
  do {                                                                       \
    _Pragma("unroll")                                                        \
    for (int j = 0; j < 4; j++) {                                            \
      GLL(gA[j] + (t) * 64, lds + (base) + (tid + j * 256) * 16);            \
      GLL(gB[j] + (t) * 64, lds + (base) + 16384 + (tid + j * 256) * 16);    \
    }                                                                        \
  } while (0)

  const int s = l & 15, g = l >> 4;
  int aRd[4], bRd[4], cOf[2];
#pragma unroll
  for (int i = 0; i < 4; i++) {
    aRd[i] = (wr * 64 + i * 16 + s) * 128;
    bRd[i] = 16384 + (wc * 64 + i * 16 + s) * 128;
  }
  cOf[0] = ((g + 0) ^ (s & 7)) * 16;
  cOf[1] = ((g + 4) ^ (s & 7)) * 16;

  f32x4 acc[4][4] = {};
  const int nt = Kloop / 64;

  LSTG(0, 0);
  for (int t = 0; t < nt; ++t) {
    __syncthreads();
    if (t + 1 < nt) LSTG(t + 1, ((t + 1) & 1) * 32768);
    const int base = (t & 1) * 32768;
#pragma unroll
    for (int ks = 0; ks < 2; ++ks) {
      bf16x8 av[4], bv[4];
#pragma unroll
      for (int i = 0; i < 4; ++i) {
        av[i] = *(const bf16x8*)(lds + base + aRd[i] + cOf[ks]);
        bv[i] = *(const bf16x8*)(lds + base + bRd[i] + cOf[ks]);
      }
#pragma unroll
      for (int i = 0; i < 4; ++i)
#pragma unroll
        for (int j = 0; j < 4; ++j)
          acc[i][j] = MF(av[i], bv[j], acc[i][j]);
    }
  }

#pragma unroll
  for (int fm = 0; fm < 4; ++fm) {
    const int row0 = m0 + wr * 64 + fm * 16 + (l >> 4) * 4;
#pragma unroll
    for (int fn = 0; fn < 4; ++fn) {
      const int col = n0 + wc * 64 + fn * 16 + (l & 15);
      if (col >= Nloc) continue;
      float bi = 0.f;
      if (EPI == EPI_QKV || EPI == EPI_BIAS_GELU) bi = bias[col];
      if (EPI == EPI_QKV && col >= 2 * Dm) {
        const int hh = (col - 2 * Dm) >> 6, dd = col & 63;
        const int bI = row0 >> 10, t0 = row0 & (Tt - 1);
        ushort4 o4;
        o4.x = f2bf(acc[fm][fn][0] + bi);
        o4.y = f2bf(acc[fm][fn][1] + bi);
        o4.z = f2bf(acc[fm][fn][2] + bi);
        o4.w = f2bf(acc[fm][fn][3] + bi);
        *(ushort4*)((ushort*)Cv2 +
                    ((size_t)((bI * Hh + hh) * 64 + dd)) * Tt + t0) = o4;
        continue;
      }
#pragma unroll
      for (int r = 0; r < 4; ++r) {
        float v = acc[fm][fn][r] + bi;
        const size_t off = (size_t)(row0 + r) * ldC + col;
        if (EPI == EPI_BIAS_GELU) {
          v = 0.5f * v * (1.f + erff(v * 0.70710678118654752f));
          ((ushort*)Cv)[off] = f2bf(v);
        } else if (EPI == EPI_QKV) {
          ((ushort*)Cv)[off] = f2bf(v);
        } else if (EPI == EPI_PART) {
          ((float*)Cv)[(size_t)z * ROWS * ldC + off] = v;
        } else {
          ((float*)Cv)[off] = v;
        }
      }
    }
  }
#undef LSTG
}

// ---------------------------------------------------------------------------
// Head GEMM — 8-phase counted-vmcnt schedule (unchanged).
// ---------------------------------------------------------------------------
__global__ __launch_bounds__(512, 2) void gemm_head8(
    const ushort* __restrict__ A, const ushort* __restrict__ B,
    float* __restrict__ C) {
  __shared__ char lds[131072];
  const int tid = threadIdx.x;
  const int l = tid & 63;
  const int wid = __builtin_amdgcn_readfirstlane(tid >> 6);
  const int wm = wid >> 2, wn = wid & 3;
  const int s = l & 15, g = l >> 4;

  const int bid = blockIdx.x;
  const int swz = (bid & 7) * 197 + (bid >> 3);
  const int pan = swz >> 3, mrw = swz & 7;
  const int m0 = mrw * 256;
  const int n0 = pan * 256;

  const int r0 = tid >> 3;
  const int q0 = (tid & 7) ^ (r0 & 7);
  const ushort* pA0 = A + (size_t)(m0 + r0) * Dm + q0 * 8;
  const ushort* pA1 = pA0 + (size_t)64 * Dm;
  const ushort* pB[2][2];
  pB[0][0] = B + (size_t)min(n0 + r0, Vv - 1) * Dm + q0 * 8;
  pB[0][1] = B + (size_t)min(n0 + 64 + r0, Vv - 1) * Dm + q0 * 8;
  pB[1][0] = B + (size_t)min(n0 + 128 + r0, Vv - 1) * Dm + q0 * 8;
  pB[1][1] = B + (size_t)min(n0 + 192 + r0, Vv - 1) * Dm + q0 * 8;

#define STG_A(t, h) do { if ((t) < 12) {                                     \
    char* _d = lds + ((((t) & 1) * 2 + (h)) * 16384);                        \
    GLL(pA0 + (size_t)(h) * 98304 + (t) * 64, _d + tid * 16);                \
    GLL(pA1 + (size_t)(h) * 98304 + (t) * 64, _d + 8192 + tid * 16);         \
  }} while (0)
#define STG_B(t, h) do { if ((t) < 12) {                                     \
    char* _d = lds + 65536 + ((((t) & 1) * 2 + (h)) * 16384);                \
    GLL(pB[h][0] + (t) * 64, _d + tid * 16);                                 \
    GLL(pB[h][1] + (t) * 64, _d + 8192 + tid * 16);                          \
  }} while (0)

  const int aK0 = ((0 * 4 + g) ^ (s & 7)) * 16;
  const int aK1 = ((1 * 4 + g) ^ (s & 7)) * 16;
  const int aBase = wm * 16384 + s * 128;
  const int bBase = 65536 + (wn >> 1) * 16384 + (wn & 1) * 8192 + s * 128;

  f32x4 acc[8][4] = {};
  bf16x8 bv[4][2];

#define PH(t, p, STAGES, VMC)                                                \
  {                                                                          \
    const int cur = ((t) & 1) * 32768;                                       \
    if ((p) == 1) {                                                          \
      _Pragma("unroll")                                                      \
      for (int fn = 0; fn < 4; fn++) {                                       \
        bv[fn][0] = *(const bf16x8*)(lds + cur + bBase + fn * 2048 + aK0);   \
        bv[fn][1] = *(const bf16x8*)(lds + cur + bBase + fn * 2048 + aK1);   \
      }                                                                      \
    }                                                                        \
    bf16x8 a00 = *(const bf16x8*)(lds + cur + aBase + (2*(p)-2)*2048 + aK0); \
    bf16x8 a01 = *(const bf16x8*)(lds + cur + aBase + (2*(p)-2)*2048 + aK1); \
    bf16x8 a10 = *(const bf16x8*)(lds + cur + aBase + (2*(p)-1)*2048 + aK0); \
    bf16x8 a11 = *(const bf16x8*)(lds + cur + aBase + (2*(p)-1)*2048 + aK1); \
    STAGES;                                                                  \
    __builtin_amdgcn_s_barrier();                                            \
    asm volatile("s_waitcnt lgkmcnt(0)" ::: "memory");                       \
    __builtin_amdgcn_sched_barrier(0);                                       \
    __builtin_amdgcn_s_setprio(1);                                           \
    _Pragma("unroll")                                                        \
    for (int fn = 0; fn < 4; fn++) {                                         \
      acc[2*(p)-2][fn] = MF(a00, bv[fn][0], acc[2*(p)-2][fn]);               \
      acc[2*(p)-2][fn] = MF(a01, bv[fn][1], acc[2*(p)-2][fn]);               \
      acc[2*(p)-1][fn] = MF(a10, bv[fn][0], acc[2*(p)-1][fn]);               \
      acc[2*(p)-1][fn] = MF(a11, bv[fn][1], acc[2*(p)-1][fn]);               \
    }                                                                        \
    __builtin_amdgcn_s_setprio(0);                                           \
    VMC;                                                                     \
    __builtin_amdgcn_s_barrier();                                            \
  }

  STG_B(0, 0); STG_B(0, 1); STG_A(0, 0); STG_A(0, 1); STG_B(1, 0); STG_B(1, 1);
  asm volatile("s_waitcnt vmcnt(4)" ::: "memory");
  __builtin_amdgcn_s_barrier();

#pragma unroll 1
  for (int i = 0; i < 6; ++i) {
    const int t0 = 2 * i, t1 = 2 * i + 1, t2 = 2 * i + 2, t3 = 2 * i + 3;
    PH(t0, 1, { STG_A(t1, 0); }, {});
    PH(t0, 2, { STG_A(t1, 1); STG_B(t2, 0); }, {});
    PH(t0, 3, { STG_B(t2, 1); }, {});
    if (i < 5) {
      PH(t0, 4, {}, { asm volatile("s_waitcnt vmcnt(4)" ::: "memory"); });
    } else {
      PH(t0, 4, {}, { asm volatile("s_waitcnt vmcnt(0)" ::: "memory"); });
    }
    PH(t1, 1, { STG_A(t2, 0); }, {});
    PH(t1, 2, { STG_A(t2, 1); }, {});
    PH(t1, 3, { STG_B(t3, 0); }, {});
    if (i < 5) {
      PH(t1, 4, { STG_B(t3, 1); },
         { asm volatile("s_waitcnt vmcnt(4)" ::: "memory"); });
    } else {
      PH(t1, 4, {}, {});
    }
  }

#pragma unroll
  for (int fm = 0; fm < 8; ++fm) {
    const int row0 = m0 + wm * 128 + fm * 16 + g * 4;
#pragma unroll
    for (int fn = 0; fn < 4; ++fn) {
      const int col = n0 + wn * 64 + fn * 16 + s;
      if (col >= Vv) continue;
#pragma unroll
      for (int r = 0; r < 4; ++r)
        C[(size_t)(row0 + r) * Vv + col] = acc[fm][fn][r];
    }
  }
#undef PH
#undef STG_A
#undef STG_B
}

// ---------------------------------------------------------------------------
// MFMA flash attention — staged (R16/R17 version, restored).
// ---------------------------------------------------------------------------
__global__ __launch_bounds__(128) void attn_mfma(
    const ushort* __restrict__ qkv, const ushort* __restrict__ vTg,
    ushort* __restrict__ y) {
  __shared__ char lds[36864];
  const int tid = threadIdx.x;
  const int l = tid & 63;
  const int w = tid >> 6;
  const int s = l & 15, g = l >> 4;
  const int bq = gridDim.x - 1 - blockIdx.x;
  const int h = blockIdx.y, b = blockIdx.z;
  const int bh = b * Hh + h;

  const int qrow = bq * 32 + w * 16 + s;
  const ushort* qp = qkv + (size_t)(b * Tt + qrow) * 2304 + h * 64 + g * 8;
  const bf16x8 aq0 = *(const bf16x8*)qp;
  const bf16x8 aq1 = *(const bf16x8*)(qp + 32);

  size_t gofs[8];
#pragma unroll
  for (int i = 0; i < 8; i++) {
    const int c = tid + i * 128;
    if (i < 4) {
      const int kr = c >> 3;
      gofs[i] = (size_t)(b * Tt + kr) * 2304 + Dm + h * 64 + ((c & 7) ^ (kr & 7)) * 8;
    } else {
      const int cv = c - 512;
      const int vr = cv >> 3;
      gofs[i] = (size_t)(bh * 64 + vr) * Tt + ((cv & 7) ^ (vr & 7)) * 8;
    }
  }

#define ASTAGE(kt, base)                                                     \
  do {                                                                       \
    _Pragma("unroll")                                                        \
    for (int i = 0; i < 8; i++) {                                            \
      const ushort* p = (i < 4) ? (qkv + gofs[i] + (size_t)(kt) * 147456)    \
                                : (vTg + gofs[i] + (kt) * 64);               \
      GLL(p, lds + (base) + tid * 16 + i * 2048);                            \
    }                                                                        \
  } while (0)

  f32x4 oc[4] = {};
  float mrun[4], lrun[4];
#pragma unroll
  for (int r = 0; r < 4; r++) { mrun[r] = -INFINITY; lrun[r] = 0.f; }

  const int pB = 32768 + w * 2048;
  const int kSw = (s & 7);
  const int nkt = (bq >> 1) + 1;

  ASTAGE(0, 0);
  for (int kt = 0; kt < nkt; ++kt) {
    __syncthreads();
    if (kt + 1 < nkt) ASTAGE(kt + 1, ((kt + 1) & 1) * 16384);
    const int cur = (kt & 1) * 16384;

    f32x4 sc[4];
    __builtin_amdgcn_s_setprio(1);
#pragma unroll
    for (int jn = 0; jn < 4; jn++) {
      const int krow = cur + (jn * 16 + s) * 128;
      const bf16x8 bk0 = *(const bf16x8*)(lds + krow + ((g ^ kSw) * 16));
      const bf16x8 bk1 = *(const bf16x8*)(lds + krow + (((4 + g) ^ kSw) * 16));
      f32x4 z = {};
      z = MF(aq0, bk0, z);
      z = MF(aq1, bk1, z);
      sc[jn] = z;
    }
    __builtin_amdgcn_s_setprio(0);

    float cr[4];
    const bool diag = (kt == nkt - 1);
#pragma unroll
    for (int r = 0; r < 4; r++) {
      const int rowg = bq * 32 + w * 16 + g * 4 + r;
      float v[4];
#pragma unroll
      for (int jn = 0; jn < 4; jn++) {
        v[jn] = sc[jn][r] * 0.125f;
        if (diag && (kt * 64 + jn * 16 + s) > rowg) v[jn] = -INFINITY;
      }
      float mx = fmaxf(fmaxf(v[0], v[1]), fmaxf(v[2], v[3]));
      mx = fmaxf(mx, __shfl_xor(mx, 1));
      mx = fmaxf(mx, __shfl_xor(mx, 2));
      mx = fmaxf(mx, __shfl_xor(mx, 4));
      mx = fmaxf(mx, __shfl_xor(mx, 8));
      const float mnew = fmaxf(mrun[r], mx);
      const float corr = __expf(mrun[r] - mnew);
      mrun[r] = mnew;
      float ps = 0.f;
#pragma unroll
      for (int jn = 0; jn < 4; jn++) {
        const float p = __expf(v[jn] - mnew);
        ps += p;
        *(ushort*)(lds + pB + (g * 4 + r) * 128 +
                   (((2 * jn + (s >> 3)) ^ g) * 16) + (s & 7) * 2) = f2bf(p);
      }
      ps += __shfl_xor(ps, 1);
      ps += __shfl_xor(ps, 2);
      ps += __shfl_xor(ps, 4);
      ps += __shfl_xor(ps, 8);
      lrun[r] = lrun[r] * corr + ps;
      cr[r] = corr;
    }

    const float c01 = (s & 1) ? cr[1] : cr[0];
    const float c23 = (s & 1) ? cr[3] : cr[2];
    const float csel = (s & 2) ? c23 : c01;
    const float ccol = __shfl(csel, ((s >> 2) << 4) | s);
#pragma unroll
    for (int fm = 0; fm < 4; fm++) {
      oc[fm][0] *= ccol; oc[fm][1] *= ccol;
      oc[fm][2] *= ccol; oc[fm][3] *= ccol;
    }

    const bf16x8 bp0 = *(const bf16x8*)(lds + pB + s * 128 + ((g ^ (s >> 2)) * 16));
    const bf16x8 bp1 = *(const bf16x8*)(lds + pB + s * 128 + (((4 + g) ^ (s >> 2)) * 16));
    __builtin_amdgcn_s_setprio(1);
#pragma unroll
    for (int fm = 0; fm < 4; fm++) {
      const int vrow = cur + 8192 + (fm * 16 + s) * 128;
      const bf16x8 av0 = *(const bf16x8*)(lds + vrow + ((g ^ kSw) * 16));
      const bf16x8 av1 = *(const bf16x8*)(lds + vrow + (((4 + g) ^ kSw) * 16));
      oc[fm] = MF(av0, bp0, oc[fm]);
      oc[fm] = MF(av1, bp1, oc[fm]);
    }
    __builtin_amdgcn_s_setprio(0);
  }

  float li[4];
#pragma unroll
  for (int r = 0; r < 4; r++) li[r] = 1.f / lrun[r];
  const float l01 = (s & 1) ? li[1] : li[0];
  const float l23 = (s & 1) ? li[3] : li[2];
  const float lsel = (s & 2) ? l23 : l01;
  const float lcol = __shfl(lsel, ((s >> 2) << 4) | s);
  ushort* yp = y + (size_t)(b * Tt + qrow) * Dm + h * 64;
#pragma unroll
  for (int fm = 0; fm < 4; fm++) {
    ushort4 o4;
    o4.x = f2bf(oc[fm][0] * lcol);
    o4.y = f2bf(oc[fm][1] * lcol);
    o4.z = f2bf(oc[fm][2] * lcol);
    o4.w = f2bf(oc[fm][3] * lcol);
    *(ushort4*)(yp + fm * 16 + g * 4) = o4;
  }
}

// ---------------------------------------------------------------------------
extern "C" void kernel_launch(void* const* d_in, const int* in_sizes, int n_in,
                              void* d_out, int out_size, void* d_ws, size_t ws_size,
                              hipStream_t stream) {
  const int* idx = (const int*)d_in[0];
  const float* tok = (const float*)d_in[1];
  const float* pos = (const float*)d_in[2];
  const float* ln1w = (const float*)d_in[3];
  const float* ln1b = (const float*)d_in[4];
  const float* qkvw = (const float*)d_in[5];
  const float* qkvb = (const float*)d_in[6];
  const float* projw = (const float*)d_in[7];
  const float* projb = (const float*)d_in[8];
  const float* ln2w = (const float*)d_in[9];
  const float* ln2b = (const float*)d_in[10];
  const float* ff1w = (const float*)d_in[11];
  const float* ff1b = (const float*)d_in[12];
  const float* ff2w = (const float*)d_in[13];
  const float* ff2b = (const float*)d_in[14];
  const float* lnfw = (const float*)d_in[15];
  const float* lnfb = (const float*)d_in[16];
  const float* headw = (const float*)d_in[17];
  float* out = (float*)d_out;

  char* ws = (char*)d_ws;
  ushort* h    = (ushort*)ws;                    // [2048][768] bf16
  float*  x    = (float*)(ws + 3145728);         // [2048][768] fp32
  ushort* y    = (ushort*)(ws + 9437184);        // [2048][768] bf16
  ushort* qkv  = (ushort*)(ws + 12582912);       // [2048][2304] bf16
  ushort* vTg  = (ushort*)(ws + 22020096);       // [24][64][1024] bf16
  ushort* ff   = (ushort*)(ws + 25165824);       // [2048][4096] bf16
  ushort* wb   = (ushort*)(ws + 41943040);       // weights bf16, per-layer blocks
  float* projPart = (float*)(ws + 326755840);    // 4 x 6.29MB
  float* ff2Part  = (float*)(ws + 351921664);    // 4 x 6.29MB

  ushort* headwb = wb + (size_t)Ll * LWE;        // = wb + 103809024

  convert_pre<<<2048, 256, 0, stream>>>(qkvw, projw, ff1w, ff2w, headw, wb);
  embed_ln<<<ROWS, 256, 0, stream>>>(idx, tok, pos, ln1w, ln1b, x, h);

  for (int l = 0; l < Ll; l++) {
    ushort* wl = wb + (size_t)l * LWE;
    const bool hasN = (l + 1 < Ll);
    const float* nq  = hasN ? qkvw + (size_t)(l + 1) * 3 * Dm * Dm : nullptr;
    const float* np  = hasN ? projw + (size_t)(l + 1) * Dm * Dm : nullptr;
    const float* nf1 = hasN ? ff1w + (size_t)(l + 1) * DFF * Dm : nullptr;
    const float* nf2 = hasN ? ff2w + (size_t)(l + 1) * Dm * DFF : nullptr;
    ushort* nd = hasN ? wb + (size_t)(l + 1) * LWE : nullptr;

    gemm_mfma<EPI_QKV><<<dim3(26, 16), 256, 0, stream>>>(
        h, wl, qkvb + l * 3 * Dm, qkv, vTg, Dm, Dm, 3 * Dm, 3 * Dm,
        nq, np, nf1, nf2, nd);
    attn_mfma<<<dim3(32, Hh, Bb), 128, 0, stream>>>(qkv, vTg, y);
    gemm_mfma<EPI_PART><<<dim3(6, 16, 4), 256, 0, stream>>>(
        y, wl + oPROJL, nullptr, projPart, nullptr, Dm / 4, Dm, Dm, Dm,
        nullptr, nullptr, nullptr, nullptr, nullptr);
    red_ln<<<ROWS, 192, 0, stream>>>(projPart, 4, projb + l * Dm, x,
                                     ln2w + l * Dm, ln2b + l * Dm, h);
    gemm_mfma<EPI_BIAS_GELU><<<dim3(32, 16), 256, 0, stream>>>(
        h, wl + oFF1L, ff1b + l * DFF, ff, nullptr, Dm, Dm, DFF, DFF,
        nullptr, nullptr, nullptr, nullptr, nullptr);
    gemm_mfma<EPI_PART><<<dim3(6, 16, 4), 256, 0, stream>>>(
        ff, wl + oFF2L, nullptr, ff2Part, nullptr, DFF / 4, DFF, Dm, Dm,
        nullptr, nullptr, nullptr, nullptr, nullptr);
    const float* nw = (l == Ll - 1) ? lnfw : ln1w + (l + 1) * Dm;
    const float* nb = (l == Ll - 1) ? lnfb : ln1b + (l + 1) * Dm;
    red_ln<<<ROWS, 192, 0, stream>>>(ff2Part, 4, ff2b + l * Dm, x, nw, nb, h);
  }

  gemm_head8<<<1576, 512, 0, stream>>>(h, headwb, out);
}

// Round 20
// 1945.335 us; speedup vs baseline: 1.0340x; 1.0340x over previous
//
#include <hip/hip_runtime.h>
#include <hip/hip_bf16.h>
#include <math.h>

#define Dm 768
#define Tt 1024
#define Bb 2
#define Hh 12
#define DFF 4096
#define Ll 12
#define Vv 50257
#define ROWS (Bb*Tt)   // 2048
#define LN_EPS 1e-5f

// per-layer weight block (elems): [qkv 1769472 | proj 589824 | ff1 3145728 | ff2 3145728]
#define LWE 8650752
#define oPROJL 1769472
#define oFF1L 2359296
#define oFF2L 5505024
// float4 cumulative within a layer block
#define L4_Q 442368
#define L4_P 589824
#define L4_F1 1376256
#define L4_ALL 2162688
#define HEAD4 9649344          // head float4 count
#define HEADD4 25952256        // head dst offset in wb (float4 units)

typedef unsigned int uint;
typedef unsigned short ushort;
typedef float f32x4 __attribute__((ext_vector_type(4)));
typedef short bf16x8 __attribute__((ext_vector_type(8)));
typedef ushort us8 __attribute__((ext_vector_type(8)));

__device__ __forceinline__ ushort f2bf(float f) {
  uint u = __builtin_bit_cast(uint, f);
  u += 0x7FFFu + ((u >> 16) & 1u);   // RNE
  return (ushort)(u >> 16);
}

__device__ __forceinline__ ushort4 cvt4(float4 v) {
  ushort4 o;
  o.x = f2bf(v.x); o.y = f2bf(v.y); o.z = f2bf(v.z); o.w = f2bf(v.w);
  return o;
}

#define GLL(gp, lp)                                                          \
  __builtin_amdgcn_global_load_lds(                                          \
      (const __attribute__((address_space(1))) uint*)(gp),                   \
      (__attribute__((address_space(3))) uint*)(lp), 16, 0, 0)

#define MF(a, b, c) __builtin_amdgcn_mfma_f32_16x16x32_bf16(a, b, c, 0, 0, 0)

// ---------------------------------------------------------------------------
// Fused embedding + LayerNorm
// ---------------------------------------------------------------------------
__global__ __launch_bounds__(256) void embed_ln(
    const int* __restrict__ idx, const float* __restrict__ tok,
    const float* __restrict__ pos, const float* __restrict__ w,
    const float* __restrict__ b, float* __restrict__ x,
    ushort* __restrict__ out) {
  const int row = blockIdx.x;
  const int t = row & (Tt - 1);
  const int tid = threadIdx.x;
  const float* tsrc = tok + (size_t)idx[row] * Dm;
  const float* psrc = pos + (size_t)t * Dm;
  float v[3];
  float sum = 0.f, sq = 0.f;
#pragma unroll
  for (int i = 0; i < 3; i++) {
    const int d = tid + i * 256;
    v[i] = tsrc[d] + psrc[d];
    x[(size_t)row * Dm + d] = v[i];
    sum += v[i]; sq += v[i] * v[i];
  }
#pragma unroll
  for (int off = 32; off > 0; off >>= 1) {
    sum += __shfl_xor(sum, off);
    sq  += __shfl_xor(sq, off);
  }
  __shared__ float red[8];
  const int wid = tid >> 6, lane = tid & 63;
  if (lane == 0) { red[wid] = sum; red[wid + 4] = sq; }
  __syncthreads();
  sum = red[0] + red[1] + red[2] + red[3];
  sq  = red[4] + red[5] + red[6] + red[7];
  const float mu = sum * (1.f / Dm);
  const float var = sq * (1.f / Dm) - mu * mu;
  const float rstd = rsqrtf(var + LN_EPS);
  ushort* dst = out + (size_t)row * Dm;
#pragma unroll
  for (int i = 0; i < 3; i++) {
    const int d = tid + i * 256;
    dst[d] = f2bf((v[i] - mu) * rstd * w[d] + b[d]);
  }
}

// ---------------------------------------------------------------------------
// Fused split-K reduce + bias + residual + LayerNorm -> bf16 h (192 thr)
// ---------------------------------------------------------------------------
__global__ __launch_bounds__(192) void red_ln(
    const float* __restrict__ part, int nsk, const float* __restrict__ bias,
    float* __restrict__ x, const float* __restrict__ w,
    const float* __restrict__ b, ushort* __restrict__ out) {
  const int row = blockIdx.x;
  const int tid = threadIdx.x;
  const size_t o4 = (size_t)row * 192 + tid;
  float4 xv = ((const float4*)x)[o4];
  const float4 b4 = ((const float4*)bias)[tid];
  xv.x += b4.x; xv.y += b4.y; xv.z += b4.z; xv.w += b4.w;
  for (int k = 0; k < nsk; k++) {
    const float4 p = ((const float4*)part)[(size_t)k * ROWS * 192 + o4];
    xv.x += p.x; xv.y += p.y; xv.z += p.z; xv.w += p.w;
  }
  ((float4*)x)[o4] = xv;
  float sum = xv.x + xv.y + xv.z + xv.w;
  float sq = xv.x * xv.x + xv.y * xv.y + xv.z * xv.z + xv.w * xv.w;
#pragma unroll
  for (int off = 32; off > 0; off >>= 1) {
    sum += __shfl_xor(sum, off);
    sq  += __shfl_xor(sq, off);
  }
  __shared__ float red[6];
  const int wid = tid >> 6, lane = tid & 63;
  if (lane == 0) { red[wid] = sum; red[wid + 3] = sq; }
  __syncthreads();
  sum = red[0] + red[1] + red[2];
  sq  = red[3] + red[4] + red[5];
  const float mu = sum * (1.f / Dm);
  const float var = sq * (1.f / Dm) - mu * mu;
  const float rstd = rsqrtf(var + LN_EPS);
  const float4 w4 = ((const float4*)w)[tid];
  const float4 bb4 = ((const float4*)b)[tid];
  ushort4 o;
  o.x = f2bf((xv.x - mu) * rstd * w4.x + bb4.x);
  o.y = f2bf((xv.y - mu) * rstd * w4.y + bb4.y);
  o.z = f2bf((xv.z - mu) * rstd * w4.z + bb4.z);
  o.w = f2bf((xv.w - mu) * rstd * w4.w + bb4.w);
  ((ushort4*)out)[o4] = o;
}

// ---------------------------------------------------------------------------
// Pre-pass converter: layer 0 block + head.
// ---------------------------------------------------------------------------
__global__ __launch_bounds__(256) void convert_pre(
    const float* __restrict__ q, const float* __restrict__ p,
    const float* __restrict__ f1, const float* __restrict__ f2,
    const float* __restrict__ hd, ushort* __restrict__ wb) {
  const int total = L4_ALL + HEAD4;
  const int stride = gridDim.x * 256;
  for (int i = blockIdx.x * 256 + threadIdx.x; i < total; i += stride) {
    const float* s; int j; size_t d;
    if (i < L4_Q) { s = q; j = i; d = i; }
    else if (i < L4_P) { s = p; j = i - L4_Q; d = i; }
    else if (i < L4_F1) { s = f1; j = i - L4_P; d = i; }
    else if (i < L4_ALL) { s = f2; j = i - L4_F1; d = i; }
    else { s = hd; j = i - L4_ALL; d = (size_t)HEADD4 + j; }
    ((ushort4*)wb)[d] = cvt4(((const float4*)s)[j]);
  }
}

// ---------------------------------------------------------------------------
// bf16 MFMA GEMM (loop GEMMs) — BK=64. EPI_QKV hosts 128 converter blocks
// (bx>=18) converting the NEXT layer's weights (register-light 1-wide loop:
// 4-wide variant inflated shared-kernel VGPRs and regressed, R19).
// ---------------------------------------------------------------------------
#define EPI_QKV 0
#define EPI_PART 1
#define EPI_BIAS_GELU 2
#define EPI_NONE 3

template <int EPI>
__global__ __launch_bounds__(256) void gemm_mfma(
    const ushort* __restrict__ A, const ushort* __restrict__ B,
    const float* __restrict__ bias, void* __restrict__ Cv,
    void* __restrict__ Cv2, int Kloop, int Kstr, int Nloc, int ldC,
    const float* __restrict__ nq, const float* __restrict__ np,
    const float* __restrict__ nf1, const float* __restrict__ nf2,
    ushort* __restrict__ ndst) {
  __shared__ char lds[65536];           // 2 x (A 16KB + B 16KB)
  const int tid = threadIdx.x;

  if (EPI == EPI_QKV && blockIdx.x >= 18) {
    // ---- converter block: next layer's weights fp32 -> bf16 ----
    if (nq != nullptr) {
      const int wkr = (blockIdx.x - 18) * 16 + blockIdx.y;   // 0..127
      for (int i = wkr * 256 + tid; i < L4_ALL; i += 128 * 256) {
        const float* s; int j;
        if (i < L4_Q) { s = nq; j = i; }
        else if (i < L4_P) { s = np; j = i - L4_Q; }
        else if (i < L4_F1) { s = nf1; j = i - L4_P; }
        else { s = nf2; j = i - L4_F1; }
        ((ushort4*)ndst)[i] = cvt4(((const float4*)s)[j]);
      }
    }
    return;
  }

  const int l = tid & 63;
  const int wid = __builtin_amdgcn_readfirstlane(tid >> 6);
  const int wr = wid >> 1, wc = wid & 1;
  const int m0 = blockIdx.y * 128;
  const int n0 = blockIdx.x * 128;
  const int z = (EPI == EPI_PART) ? blockIdx.z : 0;
  if (EPI == EPI_PART) { A += (size_t)z * Kloop; B += (size_t)z * Kloop; }

  const ushort* gA[4];
  const ushort* gB[4];
#pragma unroll
  for (int j = 0; j < 4; j++) {
    const int c = tid + j * 256;
    const int r = c >> 3;
    const int q = (c & 7) ^ (r & 7);
    gA[j] = A + (size_t)(m0 + r) * Kstr + q * 8;
    const int rb = min(n0 + r, Nloc - 1);
    gB[j] = B + (size_t)rb * Kstr + q * 8;
  }

#define LSTG(t, base)                                                        \
  do {                                                                       \
    _Pragma("unroll")                                                        \
    for (int j = 0; j < 4; j++) {                                            \
      GLL(gA[j] + (t) * 64, lds + (base) + (tid + j * 256) * 16);            \
      GLL(gB[j] + (t) * 64, lds + (base) + 16384 + (tid + j * 256) * 16);    \
    }                                                                        \
  } while (0)

  const int s = l & 15, g = l >> 4;
  int aRd[4], bRd[4], cOf[2];
#pragma unroll
  for (int i = 0; i < 4; i++) {
    aRd[i] = (wr * 64 + i * 16 + s) * 128;
    bRd[i] = 16384 + (wc * 64 + i * 16 + s) * 128;
  }
  cOf[0] = ((g + 0) ^ (s & 7)) * 16;
  cOf[1] = ((g + 4) ^ (s & 7)) * 16;

  f32x4 acc[4][4] = {};
  const int nt = Kloop / 64;

  LSTG(0, 0);
  for (int t = 0; t < nt; ++t) {
    __syncthreads();
    if (t + 1 < nt) LSTG(t + 1, ((t + 1) & 1) * 32768);
    const int base = (t & 1) * 32768;
#pragma unroll
    for (int ks = 0; ks < 2; ++ks) {
      bf16x8 av[4], bv[4];
#pragma unroll
      for (int i = 0; i < 4; ++i) {
        av[i] = *(const bf16x8*)(lds + base + aRd[i] + cOf[ks]);
        bv[i] = *(const bf16x8*)(lds + base + bRd[i] + cOf[ks]);
      }
#pragma unroll
      for (int i = 0; i < 4; ++i)
#pragma unroll
        for (int j = 0; j < 4; ++j)
          acc[i][j] = MF(av[i], bv[j], acc[i][j]);
    }
  }

#pragma unroll
  for (int fm = 0; fm < 4; ++fm) {
    const int row0 = m0 + wr * 64 + fm * 16 + (l >> 4) * 4;
#pragma unroll
    for (int fn = 0; fn < 4; ++fn) {
      const int col = n0 + wc * 64 + fn * 16 + (l & 15);
      if (col >= Nloc) continue;
      float bi = 0.f;
      if (EPI == EPI_QKV || EPI == EPI_BIAS_GELU) bi = bias[col];
      if (EPI == EPI_QKV && col >= 2 * Dm) {
        const int hh = (col - 2 * Dm) >> 6, dd = col & 63;
        const int bI = row0 >> 10, t0 = row0 & (Tt - 1);
        ushort4 o4;
        o4.x = f2bf(acc[fm][fn][0] + bi);
        o4.y = f2bf(acc[fm][fn][1] + bi);
        o4.z = f2bf(acc[fm][fn][2] + bi);
        o4.w = f2bf(acc[fm][fn][3] + bi);
        *(ushort4*)((ushort*)Cv2 +
                    ((size_t)((bI * Hh + hh) * 64 + dd)) * Tt + t0) = o4;
        continue;
      }
#pragma unroll
      for (int r = 0; r < 4; ++r) {
        float v = acc[fm][fn][r] + bi;
        const size_t off = (size_t)(row0 + r) * ldC + col;
        if (EPI == EPI_BIAS_GELU) {
          v = 0.5f * v * (1.f + erff(v * 0.70710678118654752f));
          ((ushort*)Cv)[off] = f2bf(v);
        } else if (EPI == EPI_QKV) {
          ((ushort*)Cv)[off] = f2bf(v);
        } else if (EPI == EPI_PART) {
          ((float*)Cv)[(size_t)z * ROWS * ldC + off] = v;
        } else {
          ((float*)Cv)[off] = v;
        }
      }
    }
  }
#undef LSTG
}

// ---------------------------------------------------------------------------
// Head GEMM — 8-phase counted-vmcnt schedule.
// ---------------------------------------------------------------------------
__global__ __launch_bounds__(512, 2) void gemm_head8(
    const ushort* __restrict__ A, const ushort* __restrict__ B,
    float* __restrict__ C) {
  __shared__ char lds[131072];
  const int tid = threadIdx.x;
  const int l = tid & 63;
  const int wid = __builtin_amdgcn_readfirstlane(tid >> 6);
  const int wm = wid >> 2, wn = wid & 3;
  const int s = l & 15, g = l >> 4;

  const int bid = blockIdx.x;
  const int swz = (bid & 7) * 197 + (bid >> 3);
  const int pan = swz >> 3, mrw = swz & 7;
  const int m0 = mrw * 256;
  const int n0 = pan * 256;

  const int r0 = tid >> 3;
  const int q0 = (tid & 7) ^ (r0 & 7);
  const ushort* pA0 = A + (size_t)(m0 + r0) * Dm + q0 * 8;
  const ushort* pA1 = pA0 + (size_t)64 * Dm;
  const ushort* pB[2][2];
  pB[0][0] = B + (size_t)min(n0 + r0, Vv - 1) * Dm + q0 * 8;
  pB[0][1] = B + (size_t)min(n0 + 64 + r0, Vv - 1) * Dm + q0 * 8;
  pB[1][0] = B + (size_t)min(n0 + 128 + r0, Vv - 1) * Dm + q0 * 8;
  pB[1][1] = B + (size_t)min(n0 + 192 + r0, Vv - 1) * Dm + q0 * 8;

#define STG_A(t, h) do { if ((t) < 12) {                                     \
    char* _d = lds + ((((t) & 1) * 2 + (h)) * 16384);                        \
    GLL(pA0 + (size_t)(h) * 98304 + (t) * 64, _d + tid * 16);                \
    GLL(pA1 + (size_t)(h) * 98304 + (t) * 64, _d + 8192 + tid * 16);         \
  }} while (0)
#define STG_B(t, h) do { if ((t) < 12) {                                     \
    char* _d = lds + 65536 + ((((t) & 1) * 2 + (h)) * 16384);                \
    GLL(pB[h][0] + (t) * 64, _d + tid * 16);                                 \
    GLL(pB[h][1] + (t) * 64, _d + 8192 + tid * 16);                          \
  }} while (0)

  const int aK0 = ((0 * 4 + g) ^ (s & 7)) * 16;
  const int aK1 = ((1 * 4 + g) ^ (s & 7)) * 16;
  const int aBase = wm * 16384 + s * 128;
  const int bBase = 65536 + (wn >> 1) * 16384 + (wn & 1) * 8192 + s * 128;

  f32x4 acc[8][4] = {};
  bf16x8 bv[4][2];

#define PH(t, p, STAGES, VMC)                                                \
  {                                                                          \
    const int cur = ((t) & 1) * 32768;                                       \
    if ((p) == 1) {                                                          \
      _Pragma("unroll")                                                      \
      for (int fn = 0; fn < 4; fn++) {                                       \
        bv[fn][0] = *(const bf16x8*)(lds + cur + bBase + fn * 2048 + aK0);   \
        bv[fn][1] = *(const bf16x8*)(lds + cur + bBase + fn * 2048 + aK1);   \
      }                                                                      \
    }                                                                        \
    bf16x8 a00 = *(const bf16x8*)(lds + cur + aBase + (2*(p)-2)*2048 + aK0); \
    bf16x8 a01 = *(const bf16x8*)(lds + cur + aBase + (2*(p)-2)*2048 + aK1); \
    bf16x8 a10 = *(const bf16x8*)(lds + cur + aBase + (2*(p)-1)*2048 + aK0); \
    bf16x8 a11 = *(const bf16x8*)(lds + cur + aBase + (2*(p)-1)*2048 + aK1); \
    STAGES;                                                                  \
    __builtin_amdgcn_s_barrier();                                            \
    asm volatile("s_waitcnt lgkmcnt(0)" ::: "memory");                       \
    __builtin_amdgcn_sched_barrier(0);                                       \
    __builtin_amdgcn_s_setprio(1);                                           \
    _Pragma("unroll")                                                        \
    for (int fn = 0; fn < 4; fn++) {                                         \
      acc[2*(p)-2][fn] = MF(a00, bv[fn][0], acc[2*(p)-2][fn]);               \
      acc[2*(p)-2][fn] = MF(a01, bv[fn][1], acc[2*(p)-2][fn]);               \
      acc[2*(p)-1][fn] = MF(a10, bv[fn][0], acc[2*(p)-1][fn]);               \
      acc[2*(p)-1][fn] = MF(a11, bv[fn][1], acc[2*(p)-1][fn]);               \
    }                                                                        \
    __builtin_amdgcn_s_setprio(0);                                           \
    VMC;                                                                     \
    __builtin_amdgcn_s_barrier();                                            \
  }

  STG_B(0, 0); STG_B(0, 1); STG_A(0, 0); STG_A(0, 1); STG_B(1, 0); STG_B(1, 1);
  asm volatile("s_waitcnt vmcnt(4)" ::: "memory");
  __builtin_amdgcn_s_barrier();

#pragma unroll 1
  for (int i = 0; i < 6; ++i) {
    const int t0 = 2 * i, t1 = 2 * i + 1, t2 = 2 * i + 2, t3 = 2 * i + 3;
    PH(t0, 1, { STG_A(t1, 0); }, {});
    PH(t0, 2, { STG_A(t1, 1); STG_B(t2, 0); }, {});
    PH(t0, 3, { STG_B(t2, 1); }, {});
    if (i < 5) {
      PH(t0, 4, {}, { asm volatile("s_waitcnt vmcnt(4)" ::: "memory"); });
    } else {
      PH(t0, 4, {}, { asm volatile("s_waitcnt vmcnt(0)" ::: "memory"); });
    }
    PH(t1, 1, { STG_A(t2, 0); }, {});
    PH(t1, 2, { STG_A(t2, 1); }, {});
    PH(t1, 3, { STG_B(t3, 0); }, {});
    if (i < 5) {
      PH(t1, 4, { STG_B(t3, 1); },
         { asm volatile("s_waitcnt vmcnt(4)" ::: "memory"); });
    } else {
      PH(t1, 4, {}, {});
    }
  }

#pragma unroll
  for (int fm = 0; fm < 8; ++fm) {
    const int row0 = m0 + wm * 128 + fm * 16 + g * 4;
#pragma unroll
    for (int fn = 0; fn < 4; ++fn) {
      const int col = n0 + wn * 64 + fn * 16 + s;
      if (col >= Vv) continue;
#pragma unroll
      for (int r = 0; r < 4; ++r)
        C[(size_t)(row0 + r) * Vv + col] = acc[fm][fn][r];
    }
  }
#undef PH
#undef STG_A
#undef STG_B
}

// ---------------------------------------------------------------------------
// MFMA flash attention — staged, best-known.
// ---------------------------------------------------------------------------
__global__ __launch_bounds__(128) void attn_mfma(
    const ushort* __restrict__ qkv, const ushort* __restrict__ vTg,
    ushort* __restrict__ y) {
  __shared__ char lds[36864];
  const int tid = threadIdx.x;
  const int l = tid & 63;
  const int w = tid >> 6;
  const int s = l & 15, g = l >> 4;
  const int bq = gridDim.x - 1 - blockIdx.x;
  const int h = blockIdx.y, b = blockIdx.z;
  const int bh = b * Hh + h;

  const int qrow = bq * 32 + w * 16 + s;
  const ushort* qp = qkv + (size_t)(b * Tt + qrow) * 2304 + h * 64 + g * 8;
  const bf16x8 aq0 = *(const bf16x8*)qp;
  const bf16x8 aq1 = *(const bf16x8*)(qp + 32);

  size_t gofs[8];
#pragma unroll
  for (int i = 0; i < 8; i++) {
    const int c = tid + i * 128;
    if (i < 4) {
      const int kr = c >> 3;
      gofs[i] = (size_t)(b * Tt + kr) * 2304 + Dm + h * 64 + ((c & 7) ^ (kr & 7)) * 8;
    } else {
      const int cv = c - 512;
      const int vr = cv >> 3;
      gofs[i] = (size_t)(bh * 64 + vr) * Tt + ((cv & 7) ^ (vr & 7)) * 8;
    }
  }

#define ASTAGE(kt, base)                                                     \
  do {                                                                       \
    _Pragma("unroll")                                                        \
    for (int i = 0; i < 8; i++) {                                            \
      const ushort* p = (i < 4) ? (qkv + gofs[i] + (size_t)(kt) * 147456)    \
                                : (vTg + gofs[i] + (kt) * 64);               \
      GLL(p, lds + (base) + tid * 16 + i * 2048);                            \
    }                                                                        \
  } while (0)

  f32x4 oc[4] = {};
  float mrun[4], lrun[4];
#pragma unroll
  for (int r = 0; r < 4; r++) { mrun[r] = -INFINITY; lrun[r] = 0.f; }

  const int pB = 32768 + w * 2048;
  const int kSw = (s & 7);
  const int nkt = (bq >> 1) + 1;

  ASTAGE(0, 0);
  for (int kt = 0; kt < nkt; ++kt) {
    __syncthreads();
    if (kt + 1 < nkt) ASTAGE(kt + 1, ((kt + 1) & 1) * 16384);
    const int cur = (kt & 1) * 16384;

    f32x4 sc[4];
    __builtin_amdgcn_s_setprio(1);
#pragma unroll
    for (int jn = 0; jn < 4; jn++) {
      const int krow = cur + (jn * 16 + s) * 128;
      const bf16x8 bk0 = *(const bf16x8*)(lds + krow + ((g ^ kSw) * 16));
      const bf16x8 bk1 = *(const bf16x8*)(lds + krow + (((4 + g) ^ kSw) * 16));
      f32x4 z = {};
      z = MF(aq0, bk0, z);
      z = MF(aq1, bk1, z);
      sc[jn] = z;
    }
    __builtin_amdgcn_s_setprio(0);

    float cr[4];
    const bool diag = (kt == nkt - 1);
#pragma unroll
    for (int r = 0; r < 4; r++) {
      const int rowg = bq * 32 + w * 16 + g * 4 + r;
      float v[4];
#pragma unroll
      for (int jn = 0; jn < 4; jn++) {
        v[jn] = sc[jn][r] * 0.125f;
        if (diag && (kt * 64 + jn * 16 + s) > rowg) v[jn] = -INFINITY;
      }
      float mx = fmaxf(fmaxf(v[0], v[1]), fmaxf(v[2], v[3]));
      mx = fmaxf(mx, __shfl_xor(mx, 1));
      mx = fmaxf(mx, __shfl_xor(mx, 2));
      mx = fmaxf(mx, __shfl_xor(mx, 4));
      mx = fmaxf(mx, __shfl_xor(mx, 8));
      const float mnew = fmaxf(mrun[r], mx);
      const float corr = __expf(mrun[r] - mnew);
      mrun[r] = mnew;
      float ps = 0.f;
#pragma unroll
      for (int jn = 0; jn < 4; jn++) {
        const float p = __expf(v[jn] - mnew);
        ps += p;
        *(ushort*)(lds + pB + (g * 4 + r) * 128 +
                   (((2 * jn + (s >> 3)) ^ g) * 16) + (s & 7) * 2) = f2bf(p);
      }
      ps += __shfl_xor(ps, 1);
      ps += __shfl_xor(ps, 2);
      ps += __shfl_xor(ps, 4);
      ps += __shfl_xor(ps, 8);
      lrun[r] = lrun[r] * corr + ps;
      cr[r] = corr;
    }

    const float c01 = (s & 1) ? cr[1] : cr[0];
    const float c23 = (s & 1) ? cr[3] : cr[2];
    const float csel = (s & 2) ? c23 : c01;
    const float ccol = __shfl(csel, ((s >> 2) << 4) | s);
#pragma unroll
    for (int fm = 0; fm < 4; fm++) {
      oc[fm][0] *= ccol; oc[fm][1] *= ccol;
      oc[fm][2] *= ccol; oc[fm][3] *= ccol;
    }

    const bf16x8 bp0 = *(const bf16x8*)(lds + pB + s * 128 + ((g ^ (s >> 2)) * 16));
    const bf16x8 bp1 = *(const bf16x8*)(lds + pB + s * 128 + (((4 + g) ^ (s >> 2)) * 16));
    __builtin_amdgcn_s_setprio(1);
#pragma unroll
    for (int fm = 0; fm < 4; fm++) {
      const int vrow = cur + 8192 + (fm * 16 + s) * 128;
      const bf16x8 av0 = *(const bf16x8*)(lds + vrow + ((g ^ kSw) * 16));
      const bf16x8 av1 = *(const bf16x8*)(lds + vrow + (((4 + g) ^ kSw) * 16));
      oc[fm] = MF(av0, bp0, oc[fm]);
      oc[fm] = MF(av1, bp1, oc[fm]);
    }
    __builtin_amdgcn_s_setprio(0);
  }

  float li[4];
#pragma unroll
  for (int r = 0; r < 4; r++) li[r] = 1.f / lrun[r];
  const float l01 = (s & 1) ? li[1] : li[0];
  const float l23 = (s & 1) ? li[3] : li[2];
  const float lsel = (s & 2) ? l23 : l01;
  const float lcol = __shfl(lsel, ((s >> 2) << 4) | s);
  ushort* yp = y + (size_t)(b * Tt + qrow) * Dm + h * 64;
#pragma unroll
  for (int fm = 0; fm < 4; fm++) {
    ushort4 o4;
    o4.x = f2bf(oc[fm][0] * lcol);
    o4.y = f2bf(oc[fm][1] * lcol);
    o4.z = f2bf(oc[fm][2] * lcol);
    o4.w = f2bf(oc[fm][3] * lcol);
    *(ushort4*)(yp + fm * 16 + g * 4) = o4;
  }
}

// ---------------------------------------------------------------------------
extern "C" void kernel_launch(void* const* d_in, const int* in_sizes, int n_in,
                              void* d_out, int out_size, void* d_ws, size_t ws_size,
                              hipStream_t stream) {
  const int* idx = (const int*)d_in[0];
  const float* tok = (const float*)d_in[1];
  const float* pos = (const float*)d_in[2];
  const float* ln1w = (const float*)d_in[3];
  const float* ln1b = (const float*)d_in[4];
  const float* qkvw = (const float*)d_in[5];
  const float* qkvb = (const float*)d_in[6];
  const float* projw = (const float*)d_in[7];
  const float* projb = (const float*)d_in[8];
  const float* ln2w = (const float*)d_in[9];
  const float* ln2b = (const float*)d_in[10];
  const float* ff1w = (const float*)d_in[11];
  const float* ff1b = (const float*)d_in[12];
  const float* ff2w = (const float*)d_in[13];
  const float* ff2b = (const float*)d_in[14];
  const float* lnfw = (const float*)d_in[15];
  const float* lnfb = (const float*)d_in[16];
  const float* headw = (const float*)d_in[17];
  float* out = (float*)d_out;

  char* ws = (char*)d_ws;
  ushort* h    = (ushort*)ws;                    // [2048][768] bf16
  float*  x    = (float*)(ws + 3145728);         // [2048][768] fp32
  ushort* y    = (ushort*)(ws + 9437184);        // [2048][768] bf16
  ushort* qkv  = (ushort*)(ws + 12582912);       // [2048][2304] bf16
  ushort* vTg  = (ushort*)(ws + 22020096);       // [24][64][1024] bf16
  ushort* ff   = (ushort*)(ws + 25165824);       // [2048][4096] bf16
  ushort* wb   = (ushort*)(ws + 41943040);       // weights bf16, per-layer blocks
  float* projPart = (float*)(ws + 326755840);    // 4 x 6.29MB
  float* ff2Part  = (float*)(ws + 351921664);    // 4 x 6.29MB

  ushort* headwb = wb + (size_t)Ll * LWE;        // = wb + 103809024

  // pre-pass: layer 0 + head only
  convert_pre<<<2048, 256, 0, stream>>>(qkvw, projw, ff1w, ff2w, headw, wb);

  embed_ln<<<ROWS, 256, 0, stream>>>(idx, tok, pos, ln1w, ln1b, x, h);

  for (int l = 0; l < Ll; l++) {
    ushort* wl = wb + (size_t)l * LWE;
    const bool hasN = (l + 1 < Ll);
    const float* nq  = hasN ? qkvw + (size_t)(l + 1) * 3 * Dm * Dm : nullptr;
    const float* np  = hasN ? projw + (size_t)(l + 1) * Dm * Dm : nullptr;
    const float* nf1 = hasN ? ff1w + (size_t)(l + 1) * DFF * Dm : nullptr;
    const float* nf2 = hasN ? ff2w + (size_t)(l + 1) * Dm * DFF : nullptr;
    ushort* nd = hasN ? wb + (size_t)(l + 1) * LWE : nullptr;

    gemm_mfma<EPI_QKV><<<dim3(26, 16), 256, 0, stream>>>(
        h, wl, qkvb + l * 3 * Dm, qkv, vTg, Dm, Dm, 3 * Dm, 3 * Dm,
        nq, np, nf1, nf2, nd);
    attn_mfma<<<dim3(32, Hh, Bb), 128, 0, stream>>>(qkv, vTg, y);
    gemm_mfma<EPI_PART><<<dim3(6, 16, 4), 256, 0, stream>>>(
        y, wl + oPROJL, nullptr, projPart, nullptr, Dm / 4, Dm, Dm, Dm,
        nullptr, nullptr, nullptr, nullptr, nullptr);
    red_ln<<<ROWS, 192, 0, stream>>>(projPart, 4, projb + l * Dm, x,
                                     ln2w + l * Dm, ln2b + l * Dm, h);
    gemm_mfma<EPI_BIAS_GELU><<<dim3(32, 16), 256, 0, stream>>>(
        h, wl + oFF1L, ff1b + l * DFF, ff, nullptr, Dm, Dm, DFF, DFF,
        nullptr, nullptr, nullptr, nullptr, nullptr);
    gemm_mfma<EPI_PART><<<dim3(6, 16, 4), 256, 0, stream>>>(
        ff, wl + oFF2L, nullptr, ff2Part, nullptr, DFF / 4, DFF, Dm, Dm,
        nullptr, nullptr, nullptr, nullptr, nullptr);
    const float* nw = (l == Ll - 1) ? lnfw : ln1w + (l + 1) * Dm;
    const float* nb = (l == Ll - 1) ? lnfb : ln1b + (l + 1) * Dm;
    red_ln<<<ROWS, 192, 0, stream>>>(ff2Part, 4, ff2b + l * Dm, x, nw, nb, h);
  }

  gemm_head8<<<1576, 512, 0, stream>>>(h, headwb, out);
}